// Round 1
// 297.316 us; speedup vs baseline: 1.6923x; 1.6923x over previous
//
#include <hip/hip_runtime.h>
#include <hip/hip_bf16.h>

#define M_TOT 400
#define M_SHOT 100
#define KD 49152
#define DDIM 512
#define KCODE 512

using f16x4  = __attribute__((ext_vector_type(4))) _Float16;
using f16x8  = __attribute__((ext_vector_type(8))) _Float16;
using f32x16 = __attribute__((ext_vector_type(16))) float;

// ---------------- K1: encoder GEMM, f16-limb MFMA ----------------
// Block tile: 128 M x 256 N x 1536 K-slice. Grid = 4 mt * 2 ns * 32 s = 256 (1/CU).
// A and B staged in LDS as f16 limbs (converted once), double-buffered, 1 barrier/step.
// z = 2^-10 * (xh*wh) + 2^-21 * (xh*wl + xl*wh), combined before ONE atomicAdd.
__global__ __launch_bounds__(512, 2)
void k1_gemm(const float* __restrict__ xs, const float* __restrict__ xq,
             const float* __restrict__ W, float* __restrict__ z) {
    __shared__ __align__(16) _Float16 Ah[2][4][128][8];
    __shared__ __align__(16) _Float16 Al[2][4][128][8];
    __shared__ __align__(16) _Float16 Bh[2][4][256][8];
    __shared__ __align__(16) _Float16 Bl[2][4][256][8];

    const int tid   = threadIdx.x;
    const int lane  = tid & 63;
    const int wv    = tid >> 6;      // 0..7
    const int wm    = wv >> 2;       // 0..1 : 64-row block
    const int wn    = wv & 3;        // 0..3 : 64-col block
    const int l31   = lane & 31;
    const int khalf = lane >> 5;

    // XCD swizzle: all 8 blocks of one K-slice land on one XCD (L2 sharing)
    const int b   = blockIdx.x;
    const int wid = (b & 7) * 32 + (b >> 3);
    const int s   = wid >> 3;        // 0..31 K-slice
    const int mt  = (wid >> 1) & 3;  // 0..3
    const int ns  = wid & 1;         // 0..1
    const int kbase = s * 1536;
    const int mblk  = mt * 128;
    const int nbase = ns * 256;

    // A staging: 128 rows x 32 k per step = 1024 float4, 2 per thread
    int aRow[2], aKq[2];
    const float* aPtr[2];
    #pragma unroll
    for (int it = 0; it < 2; it++) {
        int f = tid + it * 512;
        aRow[it] = f >> 3;
        aKq[it]  = (f & 7) << 2;
        int gr = mblk + aRow[it];
        aPtr[it] = (gr < M_TOT)
            ? ((gr < M_SHOT) ? xs + (size_t)gr * KD : xq + (size_t)(gr - M_SHOT) * KD)
            : nullptr;
    }
    // B staging: (kslot 0..3) x (col 0..255) tasks, 2 per thread; 8 k-strided dwords each
    int bKs[2], bCol[2];
    #pragma unroll
    for (int it = 0; it < 2; it++) {
        int tsk = tid + it * 512;
        bKs[it]  = tsk >> 8;
        bCol[it] = tsk & 255;
    }

    f32x16 accA[2][2] = {};
    f32x16 accB[2][2] = {};
    float4 av[2];
    float  bv[2][8];

    // prologue: issue loads for step 0
    {
        const int k0 = kbase;
        #pragma unroll
        for (int it = 0; it < 2; it++)
            av[it] = aPtr[it] ? *(const float4*)(aPtr[it] + k0 + aKq[it])
                              : make_float4(0.f, 0.f, 0.f, 0.f);
        #pragma unroll
        for (int it = 0; it < 2; it++) {
            const float* bp = W + (size_t)(k0 + bKs[it] * 8) * DDIM + nbase + bCol[it];
            #pragma unroll
            for (int j = 0; j < 8; j++) bv[it][j] = bp[(size_t)j * DDIM];
        }
    }

    for (int t = 0; t < 48; t++) {
        const int buf = t & 1;
        // ---- convert + LDS write of step t (vmcnt waits inserted by compiler)
        #pragma unroll
        for (int it = 0; it < 2; it++) {
            float vvv[4] = {av[it].x, av[it].y, av[it].z, av[it].w};
            f16x4 hh, ll;
            #pragma unroll
            for (int q = 0; q < 4; q++) {
                _Float16 h = (_Float16)vvv[q];
                hh[q] = h;
                ll[q] = (_Float16)((vvv[q] - (float)h) * 2048.0f);
            }
            const int ks = aKq[it] >> 3, h4 = (aKq[it] >> 2) & 1;
            *(f16x4*)&Ah[buf][ks][aRow[it]][h4 * 4] = hh;
            *(f16x4*)&Al[buf][ks][aRow[it]][h4 * 4] = ll;
        }
        #pragma unroll
        for (int it = 0; it < 2; it++) {
            f16x8 hh, ll;
            #pragma unroll
            for (int j = 0; j < 8; j++) {
                float wsc = bv[it][j] * 1024.0f;
                _Float16 h = (_Float16)wsc;
                hh[j] = h;
                ll[j] = (_Float16)((wsc - (float)h) * 2048.0f);
            }
            *(f16x8*)&Bh[buf][bKs[it]][bCol[it]][0] = hh;
            *(f16x8*)&Bl[buf][bKs[it]][bCol[it]][0] = ll;
        }
        // ---- issue loads for step t+1 (stay in flight across barrier + MFMA)
        if (t + 1 < 48) {
            const int k0 = kbase + (t + 1) * 32;
            #pragma unroll
            for (int it = 0; it < 2; it++)
                av[it] = aPtr[it] ? *(const float4*)(aPtr[it] + k0 + aKq[it])
                                  : make_float4(0.f, 0.f, 0.f, 0.f);
            #pragma unroll
            for (int it = 0; it < 2; it++) {
                const float* bp = W + (size_t)(k0 + bKs[it] * 8) * DDIM + nbase + bCol[it];
                #pragma unroll
                for (int j = 0; j < 8; j++) bv[it][j] = bp[(size_t)j * DDIM];
            }
        }
        __syncthreads();
        // ---- compute step t
        #pragma unroll
        for (int ks = 0; ks < 2; ks++) {
            const int kslot = ks * 2 + khalf;
            f16x8 a_h[2], a_l[2], b_h[2], b_l[2];
            #pragma unroll
            for (int i = 0; i < 2; i++) {
                const int row = wm * 64 + i * 32 + l31;
                a_h[i] = *(const f16x8*)&Ah[buf][kslot][row][0];
                a_l[i] = *(const f16x8*)&Al[buf][kslot][row][0];
            }
            #pragma unroll
            for (int j = 0; j < 2; j++) {
                const int col = wn * 64 + j * 32 + l31;
                b_h[j] = *(const f16x8*)&Bh[buf][kslot][col][0];
                b_l[j] = *(const f16x8*)&Bl[buf][kslot][col][0];
            }
            #pragma unroll
            for (int i = 0; i < 2; i++)
                #pragma unroll
                for (int j = 0; j < 2; j++) {
                    accA[i][j] = __builtin_amdgcn_mfma_f32_32x32x16_f16(a_h[i], b_h[j], accA[i][j], 0, 0, 0);
                    accB[i][j] = __builtin_amdgcn_mfma_f32_32x32x16_f16(a_h[i], b_l[j], accB[i][j], 0, 0, 0);
                    accB[i][j] = __builtin_amdgcn_mfma_f32_32x32x16_f16(a_l[i], b_h[j], accB[i][j], 0, 0, 0);
                }
        }
        // single barrier per step is sufficient: next iter writes buf^1, whose last
        // readers (step t-1 compute) are ordered before this step's barrier.
    }

    // epilogue: C/D layout col=lane&31, row=(r&3)+8*(r>>2)+4*(lane>>5)
    #pragma unroll
    for (int i = 0; i < 2; i++) {
        const int mb = mblk + wm * 64 + i * 32 + 4 * khalf;
        #pragma unroll
        for (int j = 0; j < 2; j++) {
            const int nc = nbase + wn * 64 + j * 32 + l31;
            #pragma unroll
            for (int r = 0; r < 16; r++) {
                const int m = mb + (r & 3) + 8 * (r >> 2);
                if (m < M_TOT)
                    atomicAdd(&z[(size_t)m * DDIM + nc],
                              accA[i][j][r] * 0x1p-10f + accB[i][j][r] * 0x1p-21f);
            }
        }
    }
}

// ---------------- K2: distances + argmin ----------------
// 400 blocks = 100 row-groups x 4 code-quarters; thread = 1 code x 1 row.
// Result combined via packed u64 atomicMin: (ordered-f32 << 32) | idx  -> min dist, tie -> lowest idx.
__device__ __forceinline__ unsigned int f2ord(float f) {
    unsigned int u = __float_as_uint(f);
    return (u & 0x80000000u) ? ~u : (u | 0x80000000u);
}

__global__ __launch_bounds__(512) void k2_argmin(const float* __restrict__ z,
                                                 const float* __restrict__ bias,
                                                 const float* __restrict__ cb,
                                                 unsigned long long* __restrict__ idx64) {
    __shared__ float zsh[4][512];
    __shared__ unsigned long long red[8];
    const int tid = threadIdx.x;
    const int mg  = blockIdx.x >> 2;     // 0..99
    const int cq  = blockIdx.x & 3;      // 0..3
    const int m0  = mg * 4;
    const int k0  = cq * 128 + (tid & 127);
    const int row = tid >> 7;            // 0..3

    for (int i2 = tid; i2 < 2048; i2 += 512) {
        int r = i2 >> 9, d = i2 & 511;
        zsh[r][d] = z[(size_t)(m0 + r) * DDIM + d] + bias[d];
    }
    __syncthreads();

    float a0 = 0.f, cn = 0.f;
    for (int d = 0; d < 512; d += 4) {
        float4 zv = *(const float4*)&zsh[row][d];
        float za[4] = {zv.x, zv.y, zv.z, zv.w};
        #pragma unroll
        for (int q = 0; q < 4; q++) {
            float c = cb[(size_t)(d + q) * KCODE + k0];
            cn = fmaf(c, c, cn);
            a0 = fmaf(za[q], c, a0);
        }
    }
    float v0 = fmaf(-2.0f, a0, cn);
    unsigned long long p0 = ((unsigned long long)f2ord(v0) << 32) | (unsigned int)k0;
    #pragma unroll
    for (int off = 32; off; off >>= 1) {
        unsigned long long q0 = __shfl_down(p0, off);
        if (q0 < p0) p0 = q0;
    }
    if ((tid & 63) == 0) red[tid >> 6] = p0;
    __syncthreads();
    if (tid < 4) {
        unsigned long long a = red[tid * 2], b2 = red[tid * 2 + 1];
        atomicMin(&idx64[m0 + tid], a < b2 ? a : b2);
    }
}

// ---------------- K3: prototypes (mean over 5 shots, normalized) ----------------
__global__ __launch_bounds__(256) void k3_proto(const unsigned long long* __restrict__ idx64,
                                                const float* __restrict__ cb,
                                                float* __restrict__ proton) {
    const int bw  = blockIdx.x;   // 0..19
    const int tid = threadIdx.x;
    const int lane = tid & 63;
    const int wv  = tid >> 6;
    __shared__ float red[4];
    __shared__ int sid[5];
    if (tid < 5) sid[tid] = (int)(unsigned int)(idx64[bw * 5 + tid] & 0xFFFFFFFFull);
    __syncthreads();
    float p[2];
    #pragma unroll
    for (int j = 0; j < 2; j++) {
        int d = tid + j * 256;
        float s = 0.0f;
        #pragma unroll
        for (int ss = 0; ss < 5; ss++) s += cb[(size_t)d * KCODE + sid[ss]];
        p[j] = s * 0.2f;
    }
    float nrm = p[0] * p[0] + p[1] * p[1];
    #pragma unroll
    for (int off = 32; off; off >>= 1) nrm += __shfl_down(nrm, off);
    if (lane == 0) red[wv] = nrm;
    __syncthreads();
    float rn = rsqrtf(red[0] + red[1] + red[2] + red[3]);
    proton[(size_t)bw * 512 + tid]       = p[0] * rn;
    proton[(size_t)bw * 512 + tid + 256] = p[1] * rn;
}

// ---------------- K4: query normalize + cosine logits ----------------
__global__ __launch_bounds__(256) void k4_logits(const unsigned long long* __restrict__ idx64,
                                                 const float* __restrict__ cb,
                                                 const float* __restrict__ proton,
                                                 const float* __restrict__ tempp,
                                                 float* __restrict__ out) {
    const int n   = blockIdx.x;   // 0..299
    const int bq  = n / 75;
    const int tid = threadIdx.x;
    const int lane = tid & 63;
    const int wv  = tid >> 6;
    __shared__ float part[4][6];
    const int i = (int)(unsigned int)(idx64[M_SHOT + n] & 0xFFFFFFFFull);
    const float q0 = cb[(size_t)tid * KCODE + i];
    const float q1 = cb[(size_t)(tid + 256) * KCODE + i];

    float vals[6];
    vals[0] = q0 * q0 + q1 * q1;
    #pragma unroll
    for (int w5 = 0; w5 < 5; w5++) {
        const float* pw = proton + (size_t)(bq * 5 + w5) * 512;
        vals[1 + w5] = q0 * pw[tid] + q1 * pw[tid + 256];
    }
    #pragma unroll
    for (int j = 0; j < 6; j++) {
        float v = vals[j];
        #pragma unroll
        for (int off = 32; off; off >>= 1) v += __shfl_down(v, off);
        if (lane == 0) part[wv][j] = v;
    }
    __syncthreads();
    if (tid == 0) {
        float res[6];
        #pragma unroll
        for (int j = 0; j < 6; j++) res[j] = part[0][j] + part[1][j] + part[2][j] + part[3][j];
        const float temp = tempp[0];
        const float rn = rsqrtf(res[0]);
        #pragma unroll
        for (int w5 = 0; w5 < 5; w5++) out[n * 5 + w5] = temp * rn * res[1 + w5];
    }
}

static const void* find_by_size(void* const* d_in, const int* in_sizes, int n_in,
                                long elems) {
    for (int i = 0; i < n_in; i++) {
        long s = in_sizes[i];
        if (s == elems || s == elems * 4) return d_in[i];   // elements or f32 bytes
    }
    return nullptr;
}

extern "C" void kernel_launch(void* const* d_in, const int* in_sizes, int n_in,
                              void* d_out, int out_size, void* d_ws, size_t ws_size,
                              hipStream_t stream) {
    const float* xs   = (const float*)find_by_size(d_in, in_sizes, n_in, 4915200L);
    const float* xq   = (const float*)find_by_size(d_in, in_sizes, n_in, 14745600L);
    const float* W    = (const float*)find_by_size(d_in, in_sizes, n_in, 25165824L);
    const float* bias = (const float*)find_by_size(d_in, in_sizes, n_in, 512L);
    const float* cb   = (const float*)find_by_size(d_in, in_sizes, n_in, 262144L);
    const float* temp = (const float*)find_by_size(d_in, in_sizes, n_in, 1L);
    if (!xs || !xq || !W || !bias || !cb || !temp) {
        xs = (const float*)d_in[0]; xq = (const float*)d_in[1];
        W  = (const float*)d_in[2]; bias = (const float*)d_in[3];
        cb = (const float*)d_in[4]; temp = (const float*)d_in[5];
    }
    float* out = (float*)d_out;

    float* zf = (float*)d_ws;                                             // 204800 f32 (819200 B)
    unsigned long long* idx64 = (unsigned long long*)((char*)d_ws + 819200); // 400 u64 (3200 B)
    float* proton = (float*)((char*)d_ws + 819200 + 3200);                // 10240 f32

    hipMemsetAsync(zf, 0, 819200, stream);
    hipMemsetAsync(idx64, 0xFF, 3200, stream);
    k1_gemm<<<256, 512, 0, stream>>>(xs, xq, W, zf);
    k2_argmin<<<400, 512, 0, stream>>>(zf, bias, cb, idx64);
    k3_proto<<<20, 256, 0, stream>>>(idx64, cb, proton);
    k4_logits<<<300, 256, 0, stream>>>(idx64, cb, proton, temp, out);
}